// Round 5
// baseline (1463.991 us; speedup 1.0000x reference)
//
#include <hip/hip_runtime.h>
#include <stdint.h>

#define N_NODES 50000
#define HIDDEN  512
#define N_EDGES 200000

#define BK 32
#define LDP 40   // padded LDS row stride in bf16 elems (80B: 16B-aligned, 2-way bank alias only)

typedef __attribute__((ext_vector_type(8))) short   short8;
typedef __attribute__((ext_vector_type(4))) float   floatx4;

__device__ inline float bf2f(ushort u) {
    union { uint32_t u; float f; } v; v.u = ((uint32_t)u) << 16; return v.f;
}
__device__ inline ushort f2bf(float f) {
    union { float f; uint32_t u; } v; v.f = f;
    uint32_t r = v.u + 0x7fffu + ((v.u >> 16) & 1u);   // round-to-nearest-even
    return (ushort)(r >> 16);
}
__device__ inline floatx4 mfma16(short8 a, short8 b, floatx4 c) {
    return __builtin_amdgcn_mfma_f32_16x16x32_bf16(a, b, c, 0, 0, 0);
}
// inputs is arange(N_NODES); if harness kept int64, the int32 view is [0,0,1,0,2,0,...]
__device__ inline bool idx_is64(const int* __restrict__ inputs) {
    return inputs[1] == 0 && inputs[2] == 1;
}

// x = bf16(emb[inputs]) : 8 f32 -> 8 bf16 per thread
__global__ void k_gather(const int* __restrict__ inputs, const float* __restrict__ emb,
                         ushort* __restrict__ xb) {
    bool is64 = idx_is64(inputs);
    int t = blockIdx.x * blockDim.x + threadIdx.x;   // N_NODES*64 threads
    int row = t >> 6, s8 = (t & 63) << 3;
    if (row >= N_NODES) return;
    int srow = is64 ? inputs[2 * row] : inputs[row];
    srow = srow < 0 ? 0 : (srow >= N_NODES ? N_NODES - 1 : srow);
    const float* src = emb + (size_t)srow * HIDDEN + s8;
    float4 v0 = *(const float4*)(src);
    float4 v1 = *(const float4*)(src + 4);
    ushort o[8] = { f2bf(v0.x), f2bf(v0.y), f2bf(v0.z), f2bf(v0.w),
                    f2bf(v1.x), f2bf(v1.y), f2bf(v1.z), f2bf(v1.w) };
    *(uint4*)(xb + (size_t)row * HIDDEN + s8) = *(uint4*)o;
}

// Wt[l][j][k] = bf16(W[l][k][j])  (B^T layout, K-contiguous)
__global__ void k_cvt_w(const float* __restrict__ w, ushort* __restrict__ wt) {
    int t = blockIdx.x * blockDim.x + threadIdx.x;   // 2*512*512
    if (t >= 2 * HIDDEN * HIDDEN) return;
    int l = t >> 18;
    int rc = t & (HIDDEN * HIDDEN - 1);
    int k = rc >> 9, j = rc & 511;
    wt[(size_t)l * HIDDEN * HIDDEN + (size_t)j * HIDDEN + k] = f2bf(w[t]);
}

// generic f32 -> bf16 (8/thread); w_ih/w_hh are already [gate*H + j][k] K-contiguous
__global__ void k_cvt8(const float* __restrict__ src, ushort* __restrict__ dst, int n) {
    int t = blockIdx.x * blockDim.x + threadIdx.x;
    int base = t * 8;
    if (base >= n) return;
    float4 v0 = *(const float4*)(src + base);
    float4 v1 = *(const float4*)(src + base + 4);
    ushort o[8] = { f2bf(v0.x), f2bf(v0.y), f2bf(v0.z), f2bf(v0.w),
                    f2bf(v1.x), f2bf(v1.y), f2bf(v1.z), f2bf(v1.w) };
    *(uint4*)(dst + base) = *(uint4*)o;
}

// ---- counting sort of edges by dst (once per call; graph shared by both layers) ----
__global__ void k_hist(const int* __restrict__ inputs, const int* __restrict__ A,
                       int* __restrict__ count) {
    bool is64 = idx_is64(inputs);
    int e = blockIdx.x * blockDim.x + threadIdx.x;
    if (e >= N_EDGES) return;
    int d = is64 ? A[2 * (N_EDGES + e)] : A[N_EDGES + e];
    if (d < 0 || d >= N_NODES) return;
    atomicAdd(count + d, 1);
}

#define SCAN_T 1024
__global__ __launch_bounds__(SCAN_T) void k_scan(const int* __restrict__ count,
                                                 int* __restrict__ row_start,
                                                 int* __restrict__ cursor) {
    __shared__ int part[SCAN_T];
    const int t = threadIdx.x;
    const int chunk = (N_NODES + SCAN_T - 1) / SCAN_T;   // 49
    const int base = t * chunk;
    int s = 0;
    for (int i = 0; i < chunk; ++i) {
        int idx = base + i;
        if (idx < N_NODES) s += count[idx];
    }
    part[t] = s;
    __syncthreads();
    for (int off = 1; off < SCAN_T; off <<= 1) {
        int add = (t >= off) ? part[t - off] : 0;
        __syncthreads();
        part[t] += add;
        __syncthreads();
    }
    int running = (t == 0) ? 0 : part[t - 1];
    for (int i = 0; i < chunk; ++i) {
        int idx = base + i;
        if (idx < N_NODES) {
            row_start[idx] = running;
            cursor[idx] = running;
            running += count[idx];
        }
    }
    if (t == 0) row_start[N_NODES] = part[SCAN_T - 1];
}

__global__ void k_place(const int* __restrict__ inputs, const int* __restrict__ A,
                        int* __restrict__ cursor, int* __restrict__ esrc) {
    bool is64 = idx_is64(inputs);
    int e = blockIdx.x * blockDim.x + threadIdx.x;
    if (e >= N_EDGES) return;
    int s, d;
    if (is64) { s = A[2 * e]; d = A[2 * (N_EDGES + e)]; }
    else      { s = A[e];     d = A[N_EDGES + e]; }
    if (s < 0 || s >= N_NODES || d < 0 || d >= N_NODES) return;
    int pos = atomicAdd(cursor + d, 1);
    esrc[pos] = s;
}

// agg[n] = sum_{e: dst=n} m[src[e]] : one wave per node, lane owns 8 cols, f32 acc -> bf16
__global__ __launch_bounds__(256) void k_agg(const int* __restrict__ row_start,
                                             const int* __restrict__ esrc,
                                             const ushort* __restrict__ m,
                                             ushort* __restrict__ agg) {
    int node = blockIdx.x * 4 + (threadIdx.x >> 6);
    if (node >= N_NODES) return;
    int lane = threadIdx.x & 63;
    int q = lane << 3;
    int beg = row_start[node], end = row_start[node + 1];
    float acc[8] = {};
    for (int i = beg; i < end; ++i) {
        int s = esrc[i];
        uint4 v = *(const uint4*)(m + (size_t)s * HIDDEN + q);
        const ushort* u = (const ushort*)&v;
        #pragma unroll
        for (int j = 0; j < 8; ++j) acc[j] += bf2f(u[j]);
    }
    ushort o[8];
    #pragma unroll
    for (int j = 0; j < 8; ++j) o[j] = f2bf(acc[j]);
    *(uint4*)(agg + (size_t)node * HIDDEN + q) = *(uint4*)o;
}

// m = x @ W : 128x128 tile, 4 waves (2x2), wave-tile 64x64 (4x4 16x16 frags)
__global__ __launch_bounds__(256) void k_gemm_m(const ushort* __restrict__ xb,
                                                const ushort* __restrict__ wt,
                                                ushort* __restrict__ mOut) {
    __shared__ ushort As[128][LDP];
    __shared__ ushort Bs[128][LDP];
    const int n0 = blockIdx.x * 128, c0 = blockIdx.y * 128;
    const int t = threadIdx.x;
    const int wave = t >> 6, lane = t & 63;
    const int wm = (wave >> 1) << 6, wn = (wave & 1) << 6;
    const int fr = lane & 15, fk = (lane >> 4) << 3;
    const int lm = t >> 2, lk = (t & 3) << 3;     // 64 rows x 4 chunks per pass
    floatx4 acc[4][4] = {};

    for (int k0 = 0; k0 < HIDDEN; k0 += BK) {
        int gr0 = n0 + lm, gr1 = n0 + 64 + lm;
        uint4 a0 = {0,0,0,0}, a1 = {0,0,0,0};
        if (gr0 < N_NODES) a0 = *(const uint4*)(xb + (size_t)gr0 * HIDDEN + k0 + lk);
        if (gr1 < N_NODES) a1 = *(const uint4*)(xb + (size_t)gr1 * HIDDEN + k0 + lk);
        uint4 b0 = *(const uint4*)(wt + (size_t)(c0 + lm) * HIDDEN + k0 + lk);
        uint4 b1 = *(const uint4*)(wt + (size_t)(c0 + 64 + lm) * HIDDEN + k0 + lk);
        *(uint4*)&As[lm][lk] = a0;
        *(uint4*)&As[64 + lm][lk] = a1;
        *(uint4*)&Bs[lm][lk] = b0;
        *(uint4*)&Bs[64 + lm][lk] = b1;
        __syncthreads();
        short8 aa[4], bb[4];
        #pragma unroll
        for (int i = 0; i < 4; ++i) {
            aa[i] = *(const short8*)&As[wm + i * 16 + fr][fk];
            bb[i] = *(const short8*)&Bs[wn + i * 16 + fr][fk];
        }
        #pragma unroll
        for (int i = 0; i < 4; ++i)
            #pragma unroll
            for (int j = 0; j < 4; ++j)
                acc[i][j] = mfma16(aa[i], bb[j], acc[i][j]);
        __syncthreads();
    }
    const int er = (lane >> 4) << 2, ec = lane & 15;
    #pragma unroll
    for (int i = 0; i < 4; ++i)
        #pragma unroll
        for (int j = 0; j < 4; ++j)
            #pragma unroll
            for (int r = 0; r < 4; ++r) {
                int row = n0 + wm + i * 16 + er + r;
                if (row < N_NODES)
                    mOut[(size_t)row * HIDDEN + c0 + wn + j * 16 + ec] = f2bf(acc[i][j][r]);
            }
}

// Fused GRU: 128x64 tile, wave-tile 64x32; bf16 pre-converted weights; 4 acc sets.
__global__ __launch_bounds__(256) void k_gru(const ushort* __restrict__ agg,
                                             const ushort* __restrict__ xb_cur,
                                             const ushort* __restrict__ wih,
                                             const ushort* __restrict__ whh,
                                             const float* __restrict__ b_ih,
                                             const float* __restrict__ b_hh,
                                             ushort* __restrict__ xb_next) {
    __shared__ ushort Ag[128][LDP];
    __shared__ ushort Xs[128][LDP];
    __shared__ ushort Wsh[6][64][LDP];   // 0..2: w_ih r,z,n ; 3..5: w_hh r,z,n
    const int n0 = blockIdx.x * 128, c0 = blockIdx.y * 64;
    const int t = threadIdx.x;
    const int wave = t >> 6, lane = t & 63;
    const int wm = (wave >> 1) << 6;   // 0 / 64
    const int wn = (wave & 1) << 5;    // 0 / 32
    const int fr = lane & 15, fk = (lane >> 4) << 3;
    const int lm = t >> 2, lk = (t & 3) << 3;     // 64 rows x 4 chunks
    floatx4 a_sr[4][2] = {}, a_sz[4][2] = {}, a_in[4][2] = {}, a_hn[4][2] = {};

    for (int k0 = 0; k0 < HIDDEN; k0 += BK) {
        int gr0 = n0 + lm, gr1 = n0 + 64 + lm;
        uint4 a0 = {0,0,0,0}, a1 = {0,0,0,0}, x0 = {0,0,0,0}, x1 = {0,0,0,0};
        if (gr0 < N_NODES) {
            a0 = *(const uint4*)(agg    + (size_t)gr0 * HIDDEN + k0 + lk);
            x0 = *(const uint4*)(xb_cur + (size_t)gr0 * HIDDEN + k0 + lk);
        }
        if (gr1 < N_NODES) {
            a1 = *(const uint4*)(agg    + (size_t)gr1 * HIDDEN + k0 + lk);
            x1 = *(const uint4*)(xb_cur + (size_t)gr1 * HIDDEN + k0 + lk);
        }
        *(uint4*)&Ag[lm][lk] = a0;
        *(uint4*)&Ag[64 + lm][lk] = a1;
        *(uint4*)&Xs[lm][lk] = x0;
        *(uint4*)&Xs[64 + lm][lk] = x1;
        #pragma unroll
        for (int g = 0; g < 3; ++g) {
            *(uint4*)&Wsh[g][lm][lk] =
                *(const uint4*)(wih + (size_t)(g * HIDDEN + c0 + lm) * HIDDEN + k0 + lk);
            *(uint4*)&Wsh[3 + g][lm][lk] =
                *(const uint4*)(whh + (size_t)(g * HIDDEN + c0 + lm) * HIDDEN + k0 + lk);
        }
        __syncthreads();
        short8 aa[4], ax[4];
        #pragma unroll
        for (int i = 0; i < 4; ++i) {
            aa[i] = *(const short8*)&Ag[wm + i * 16 + fr][fk];
            ax[i] = *(const short8*)&Xs[wm + i * 16 + fr][fk];
        }
        #define GATE(g, A, ACC) { \
            short8 b0 = *(const short8*)&Wsh[g][wn + fr][fk]; \
            short8 b1 = *(const short8*)&Wsh[g][wn + 16 + fr][fk]; \
            _Pragma("unroll") \
            for (int i = 0; i < 4; ++i) { \
                ACC[i][0] = mfma16(A[i], b0, ACC[i][0]); \
                ACC[i][1] = mfma16(A[i], b1, ACC[i][1]); } }
        GATE(0, aa, a_sr)
        GATE(3, ax, a_sr)
        GATE(1, aa, a_sz)
        GATE(4, ax, a_sz)
        GATE(2, aa, a_in)
        GATE(5, ax, a_hn)
        #undef GATE
        __syncthreads();
    }
    const int er = (lane >> 4) << 2, ec = lane & 15;
    #pragma unroll
    for (int j = 0; j < 2; ++j) {
        int col = c0 + wn + j * 16 + ec;
        float bir = b_ih[col] + b_hh[col];
        float biz = b_ih[HIDDEN + col] + b_hh[HIDDEN + col];
        float bin = b_ih[2 * HIDDEN + col];
        float bhn = b_hh[2 * HIDDEN + col];
        #pragma unroll
        for (int i = 0; i < 4; ++i)
            #pragma unroll
            for (int r = 0; r < 4; ++r) {
                int row = n0 + wm + i * 16 + er + r;
                if (row >= N_NODES) continue;
                float vsr = a_sr[i][j][r] + bir;
                float vsz = a_sz[i][j][r] + biz;
                float vin = a_in[i][j][r] + bin;
                float vhn = a_hn[i][j][r] + bhn;
                float rr = 1.f / (1.f + __expf(-vsr));
                float zz = 1.f / (1.f + __expf(-vsz));
                float nn = tanhf(vin + rr * vhn);
                float h  = bf2f(xb_cur[(size_t)row * HIDDEN + col]);
                float out = (1.f - zz) * nn + zz * h;
                xb_next[(size_t)row * HIDDEN + col] = f2bf(out);
            }
    }
}

// final bf16 -> f32 into d_out
__global__ void k_cvt_out(const ushort* __restrict__ xb, float* __restrict__ out) {
    int t = blockIdx.x * blockDim.x + threadIdx.x;
    size_t base = (size_t)t * 8;
    if (base >= (size_t)N_NODES * HIDDEN) return;
    uint4 v = *(const uint4*)(xb + base);
    const ushort* u = (const ushort*)&v;
    float4 o0 = { bf2f(u[0]), bf2f(u[1]), bf2f(u[2]), bf2f(u[3]) };
    float4 o1 = { bf2f(u[4]), bf2f(u[5]), bf2f(u[6]), bf2f(u[7]) };
    *(float4*)(out + base) = o0;
    *(float4*)(out + base + 4) = o1;
}

extern "C" void kernel_launch(void* const* d_in, const int* in_sizes, int n_in,
                              void* d_out, int out_size, void* d_ws, size_t ws_size,
                              hipStream_t stream) {
    const int*   inputs = (const int*)d_in[0];
    const int*   A      = (const int*)d_in[1];
    const float* emb    = (const float*)d_in[2];
    const float* weight = (const float*)d_in[3];
    const float* w_ih   = (const float*)d_in[4];
    const float* w_hh   = (const float*)d_in[5];
    const float* b_ih   = (const float*)d_in[6];
    const float* b_hh   = (const float*)d_in[7];

    // ws: Wt 1MB + Wih/Whh bf16 3.1MB + bufA/bufB 102.4MB + sort ~1.4MB = ~108 MB.
    // bf16 agg (51.2MB) lives in d_out (102.4MB); final cvt overwrites it.
    char* ws = (char*)d_ws;
    size_t off = 0;
    auto alloc = [&](size_t bytes) { void* p = ws + off; off += (bytes + 255) & ~255ull; return p; };
    ushort* Wt        = (ushort*)alloc((size_t)2 * HIDDEN * HIDDEN * sizeof(ushort));
    ushort* WihB      = (ushort*)alloc((size_t)3 * HIDDEN * HIDDEN * sizeof(ushort));
    ushort* WhhB      = (ushort*)alloc((size_t)3 * HIDDEN * HIDDEN * sizeof(ushort));
    ushort* bufA      = (ushort*)alloc((size_t)N_NODES * HIDDEN * sizeof(ushort));
    ushort* bufB      = (ushort*)alloc((size_t)N_NODES * HIDDEN * sizeof(ushort));
    int*    count     = (int*)alloc((size_t)N_NODES * sizeof(int));
    int*    row_start = (int*)alloc((size_t)(N_NODES + 1) * sizeof(int));
    int*    cursor    = (int*)alloc((size_t)N_NODES * sizeof(int));
    int*    esrc      = (int*)alloc((size_t)N_EDGES * sizeof(int));
    ushort* agg       = (ushort*)d_out;

    const int nW = 3 * HIDDEN * HIDDEN;
    k_cvt_w<<<(2 * HIDDEN * HIDDEN + 255) / 256, 256, 0, stream>>>(weight, Wt);
    k_cvt8<<<(nW / 8 + 255) / 256, 256, 0, stream>>>(w_ih, WihB, nW);
    k_cvt8<<<(nW / 8 + 255) / 256, 256, 0, stream>>>(w_hh, WhhB, nW);
    k_gather<<<(N_NODES * 64 + 255) / 256, 256, 0, stream>>>(inputs, emb, bufA);

    hipMemsetAsync(count, 0, (size_t)N_NODES * sizeof(int), stream);
    k_hist<<<(N_EDGES + 255) / 256, 256, 0, stream>>>(inputs, A, count);
    k_scan<<<1, SCAN_T, 0, stream>>>(count, row_start, cursor);
    k_place<<<(N_EDGES + 255) / 256, 256, 0, stream>>>(inputs, A, cursor, esrc);

    dim3 gGemm((N_NODES + 127) / 128, HIDDEN / 128);
    dim3 gGru((N_NODES + 127) / 128, HIDDEN / 64);
    dim3 ga((N_NODES + 3) / 4);

    // Layer 0: x0=bufA, m0 -> bufB, agg -> d_out, GRU -> bufB
    k_gemm_m<<<gGemm, 256, 0, stream>>>(bufA, Wt, bufB);
    k_agg<<<ga, 256, 0, stream>>>(row_start, esrc, bufB, agg);
    k_gru<<<gGru, 256, 0, stream>>>(agg, bufA, WihB, WhhB, b_ih, b_hh, bufB);

    // Layer 1: x1=bufB, m1 -> bufA, agg -> d_out, GRU -> bufA
    k_gemm_m<<<gGemm, 256, 0, stream>>>(bufB, Wt + (size_t)HIDDEN * HIDDEN, bufA);
    k_agg<<<ga, 256, 0, stream>>>(row_start, esrc, bufA, agg);
    k_gru<<<gGru, 256, 0, stream>>>(agg, bufB, WihB, WhhB, b_ih, b_hh, bufA);

    k_cvt_out<<<(N_NODES * HIDDEN / 8 + 255) / 256, 256, 0, stream>>>(bufA, (float*)d_out);
}

// Round 6
// 999.708 us; speedup vs baseline: 1.4644x; 1.4644x over previous
//
#include <hip/hip_runtime.h>
#include <stdint.h>

#define N_NODES 50000
#define HIDDEN  512
#define N_EDGES 200000

#define BK 32
#define LDP 40   // padded LDS row stride in bf16 elems (80B: 16B-aligned, 2-way bank alias only)

typedef __attribute__((ext_vector_type(8))) short   short8;
typedef __attribute__((ext_vector_type(4))) float   floatx4;

__device__ inline float bf2f(ushort u) {
    union { uint32_t u; float f; } v; v.u = ((uint32_t)u) << 16; return v.f;
}
__device__ inline ushort f2bf(float f) {
    union { float f; uint32_t u; } v; v.f = f;
    uint32_t r = v.u + 0x7fffu + ((v.u >> 16) & 1u);   // round-to-nearest-even
    return (ushort)(r >> 16);
}
__device__ inline floatx4 mfma16(short8 a, short8 b, floatx4 c) {
    return __builtin_amdgcn_mfma_f32_16x16x32_bf16(a, b, c, 0, 0, 0);
}
// inputs is arange(N_NODES); if harness kept int64, the int32 view is [0,0,1,0,2,0,...]
__device__ inline bool idx_is64(const int* __restrict__ inputs) {
    return inputs[1] == 0 && inputs[2] == 1;
}

// x = bf16(emb[inputs]) : 8 f32 -> 8 bf16 per thread
__global__ void k_gather(const int* __restrict__ inputs, const float* __restrict__ emb,
                         ushort* __restrict__ xb) {
    bool is64 = idx_is64(inputs);
    int t = blockIdx.x * blockDim.x + threadIdx.x;   // N_NODES*64 threads
    int row = t >> 6, s8 = (t & 63) << 3;
    if (row >= N_NODES) return;
    int srow = is64 ? inputs[2 * row] : inputs[row];
    srow = srow < 0 ? 0 : (srow >= N_NODES ? N_NODES - 1 : srow);
    const float* src = emb + (size_t)srow * HIDDEN + s8;
    float4 v0 = *(const float4*)(src);
    float4 v1 = *(const float4*)(src + 4);
    ushort o[8] = { f2bf(v0.x), f2bf(v0.y), f2bf(v0.z), f2bf(v0.w),
                    f2bf(v1.x), f2bf(v1.y), f2bf(v1.z), f2bf(v1.w) };
    *(uint4*)(xb + (size_t)row * HIDDEN + s8) = *(uint4*)o;
}

// generic f32 -> bf16 (8/thread), row-major preserved
__global__ void k_cvt8(const float* __restrict__ src, ushort* __restrict__ dst, int n) {
    int t = blockIdx.x * blockDim.x + threadIdx.x;
    int base = t * 8;
    if (base >= n) return;
    float4 v0 = *(const float4*)(src + base);
    float4 v1 = *(const float4*)(src + base + 4);
    ushort o[8] = { f2bf(v0.x), f2bf(v0.y), f2bf(v0.z), f2bf(v0.w),
                    f2bf(v1.x), f2bf(v1.y), f2bf(v1.z), f2bf(v1.w) };
    *(uint4*)(dst + base) = *(uint4*)o;
}

// Wc[l][g][k] = sum_j wih[g][j] * W[l][k][j]   (combined gi weights, B^T layout for GRU)
// A = WihB [1536][512] contig-j ; B = Wb[l] [512][512] contig-j ; M=1536,N=512,K=512.
__global__ __launch_bounds__(256) void k_gemm_w(const ushort* __restrict__ Aw,
                                                const ushort* __restrict__ Bw,
                                                ushort* __restrict__ Cw) {
    __shared__ ushort As[128][LDP];
    __shared__ ushort Bs[128][LDP];
    const int l = blockIdx.z;
    const ushort* Bp = Bw + (size_t)l * HIDDEN * HIDDEN;
    ushort* Cp = Cw + (size_t)l * 3 * HIDDEN * HIDDEN;
    const int n0 = blockIdx.x * 128, c0 = blockIdx.y * 128;
    const int t = threadIdx.x;
    const int wave = t >> 6, lane = t & 63;
    const int wm = (wave >> 1) << 6, wn = (wave & 1) << 6;
    const int fr = lane & 15, fk = (lane >> 4) << 3;
    const int lm = t >> 2, lk = (t & 3) << 3;
    floatx4 acc[4][4] = {};

    for (int k0 = 0; k0 < HIDDEN; k0 += BK) {
        *(uint4*)&As[lm][lk]      = *(const uint4*)(Aw + (size_t)(n0 + lm) * HIDDEN + k0 + lk);
        *(uint4*)&As[64 + lm][lk] = *(const uint4*)(Aw + (size_t)(n0 + 64 + lm) * HIDDEN + k0 + lk);
        *(uint4*)&Bs[lm][lk]      = *(const uint4*)(Bp + (size_t)(c0 + lm) * HIDDEN + k0 + lk);
        *(uint4*)&Bs[64 + lm][lk] = *(const uint4*)(Bp + (size_t)(c0 + 64 + lm) * HIDDEN + k0 + lk);
        __syncthreads();
        short8 aa[4], bb[4];
        #pragma unroll
        for (int i = 0; i < 4; ++i) {
            aa[i] = *(const short8*)&As[wm + i * 16 + fr][fk];
            bb[i] = *(const short8*)&Bs[wn + i * 16 + fr][fk];
        }
        #pragma unroll
        for (int i = 0; i < 4; ++i)
            #pragma unroll
            for (int j = 0; j < 4; ++j)
                acc[i][j] = mfma16(aa[i], bb[j], acc[i][j]);
        __syncthreads();
    }
    const int er = (lane >> 4) << 2, ec = lane & 15;
    #pragma unroll
    for (int i = 0; i < 4; ++i)
        #pragma unroll
        for (int j = 0; j < 4; ++j)
            #pragma unroll
            for (int r = 0; r < 4; ++r) {
                int row = n0 + wm + i * 16 + er + r;
                Cp[(size_t)row * HIDDEN + c0 + wn + j * 16 + ec] = f2bf(acc[i][j][r]);
            }
}

// ---- counting sort of edges by dst (once per call; graph shared by both layers) ----
__global__ void k_hist(const int* __restrict__ inputs, const int* __restrict__ A,
                       int* __restrict__ count) {
    bool is64 = idx_is64(inputs);
    int e = blockIdx.x * blockDim.x + threadIdx.x;
    if (e >= N_EDGES) return;
    int d = is64 ? A[2 * (N_EDGES + e)] : A[N_EDGES + e];
    if (d < 0 || d >= N_NODES) return;
    atomicAdd(count + d, 1);
}

#define SCAN_T 1024
__global__ __launch_bounds__(SCAN_T) void k_scan(const int* __restrict__ count,
                                                 int* __restrict__ row_start,
                                                 int* __restrict__ cursor) {
    __shared__ int part[SCAN_T];
    const int t = threadIdx.x;
    const int chunk = (N_NODES + SCAN_T - 1) / SCAN_T;   // 49
    const int base = t * chunk;
    int s = 0;
    for (int i = 0; i < chunk; ++i) {
        int idx = base + i;
        if (idx < N_NODES) s += count[idx];
    }
    part[t] = s;
    __syncthreads();
    for (int off = 1; off < SCAN_T; off <<= 1) {
        int add = (t >= off) ? part[t - off] : 0;
        __syncthreads();
        part[t] += add;
        __syncthreads();
    }
    int running = (t == 0) ? 0 : part[t - 1];
    for (int i = 0; i < chunk; ++i) {
        int idx = base + i;
        if (idx < N_NODES) {
            row_start[idx] = running;
            cursor[idx] = running;
            running += count[idx];
        }
    }
    if (t == 0) row_start[N_NODES] = part[SCAN_T - 1];
}

__global__ void k_place(const int* __restrict__ inputs, const int* __restrict__ A,
                        int* __restrict__ cursor, int* __restrict__ esrc) {
    bool is64 = idx_is64(inputs);
    int e = blockIdx.x * blockDim.x + threadIdx.x;
    if (e >= N_EDGES) return;
    int s, d;
    if (is64) { s = A[2 * e]; d = A[2 * (N_EDGES + e)]; }
    else      { s = A[e];     d = A[N_EDGES + e]; }
    if (s < 0 || s >= N_NODES || d < 0 || d >= N_NODES) return;
    int pos = atomicAdd(cursor + d, 1);
    esrc[pos] = s;
}

// ax[n] = sum_{e: dst=n} x[src[e]] : one wave per node, lane owns 8 cols, f32 acc -> bf16
__global__ __launch_bounds__(256) void k_agg(const int* __restrict__ row_start,
                                             const int* __restrict__ esrc,
                                             const ushort* __restrict__ x,
                                             ushort* __restrict__ ax) {
    int node = blockIdx.x * 4 + (threadIdx.x >> 6);
    if (node >= N_NODES) return;
    int lane = threadIdx.x & 63;
    int q = lane << 3;
    int beg = row_start[node], end = row_start[node + 1];
    float acc[8] = {};
    for (int i = beg; i < end; ++i) {
        int s = esrc[i];
        uint4 v = *(const uint4*)(x + (size_t)s * HIDDEN + q);
        const ushort* u = (const ushort*)&v;
        #pragma unroll
        for (int j = 0; j < 8; ++j) acc[j] += bf2f(u[j]);
    }
    ushort o[8];
    #pragma unroll
    for (int j = 0; j < 8; ++j) o[j] = f2bf(acc[j]);
    *(uint4*)(ax + (size_t)node * HIDDEN + q) = *(uint4*)o;
}

// Fused GRU: 64x64 tile (round-4 shape), bf16 weights, 4 acc sets.
// gi = ax @ Wc_l (combined W@w_ih^T), gh = x @ w_hh^T, gates in epilogue.
template<bool F32OUT>
__global__ __launch_bounds__(256) void k_gru(const ushort* __restrict__ agg,
                                             const ushort* __restrict__ xb_cur,
                                             const ushort* __restrict__ wih,
                                             const ushort* __restrict__ whh,
                                             const float* __restrict__ b_ih,
                                             const float* __restrict__ b_hh,
                                             ushort* __restrict__ outB,
                                             float* __restrict__ outF) {
    __shared__ ushort Ag[64][LDP];
    __shared__ ushort Xs[64][LDP];
    __shared__ ushort Wsh[6][64][LDP];   // 0..2: gi r,z,n ; 3..5: w_hh r,z,n
    const int n0 = blockIdx.x * 64, c0 = blockIdx.y * 64;
    const int t = threadIdx.x;
    const int wave = t >> 6, lane = t & 63;
    const int wm = (wave >> 1) << 5, wn = (wave & 1) << 5;
    const int fr = lane & 15, fk = (lane >> 4) << 3;
    const int lm = t >> 2, lk = (t & 3) << 3;
    floatx4 a_sr[2][2] = {}, a_sz[2][2] = {}, a_in[2][2] = {}, a_hn[2][2] = {};

    for (int k0 = 0; k0 < HIDDEN; k0 += BK) {
        int gr = n0 + lm;
        uint4 av = {0, 0, 0, 0}, xv = {0, 0, 0, 0};
        if (gr < N_NODES) {
            av = *(const uint4*)(agg    + (size_t)gr * HIDDEN + k0 + lk);
            xv = *(const uint4*)(xb_cur + (size_t)gr * HIDDEN + k0 + lk);
        }
        *(uint4*)&Ag[lm][lk] = av;
        *(uint4*)&Xs[lm][lk] = xv;
        #pragma unroll
        for (int g = 0; g < 3; ++g) {
            *(uint4*)&Wsh[g][lm][lk] =
                *(const uint4*)(wih + (size_t)(g * HIDDEN + c0 + lm) * HIDDEN + k0 + lk);
            *(uint4*)&Wsh[3 + g][lm][lk] =
                *(const uint4*)(whh + (size_t)(g * HIDDEN + c0 + lm) * HIDDEN + k0 + lk);
        }
        __syncthreads();
        short8 aa[2], ax[2];
        #pragma unroll
        for (int i = 0; i < 2; ++i) {
            aa[i] = *(const short8*)&Ag[wm + i * 16 + fr][fk];
            ax[i] = *(const short8*)&Xs[wm + i * 16 + fr][fk];
        }
        #define GATE(g, A, ACC) { \
            short8 b0 = *(const short8*)&Wsh[g][wn + fr][fk]; \
            short8 b1 = *(const short8*)&Wsh[g][wn + 16 + fr][fk]; \
            _Pragma("unroll") \
            for (int i = 0; i < 2; ++i) { \
                ACC[i][0] = mfma16(A[i], b0, ACC[i][0]); \
                ACC[i][1] = mfma16(A[i], b1, ACC[i][1]); } }
        GATE(0, aa, a_sr)
        GATE(3, ax, a_sr)
        GATE(1, aa, a_sz)
        GATE(4, ax, a_sz)
        GATE(2, aa, a_in)
        GATE(5, ax, a_hn)
        #undef GATE
        __syncthreads();
    }
    const int er = (lane >> 4) << 2, ec = lane & 15;
    #pragma unroll
    for (int j = 0; j < 2; ++j) {
        int col = c0 + wn + j * 16 + ec;
        float bir = b_ih[col] + b_hh[col];
        float biz = b_ih[HIDDEN + col] + b_hh[HIDDEN + col];
        float bin = b_ih[2 * HIDDEN + col];
        float bhn = b_hh[2 * HIDDEN + col];
        #pragma unroll
        for (int i = 0; i < 2; ++i)
            #pragma unroll
            for (int r = 0; r < 4; ++r) {
                int row = n0 + wm + i * 16 + er + r;
                if (row >= N_NODES) continue;
                float vsr = a_sr[i][j][r] + bir;
                float vsz = a_sz[i][j][r] + biz;
                float vin = a_in[i][j][r] + bin;
                float vhn = a_hn[i][j][r] + bhn;
                float rr = 1.f / (1.f + __expf(-vsr));
                float zz = 1.f / (1.f + __expf(-vsz));
                float nn = tanhf(vin + rr * vhn);
                float h  = bf2f(xb_cur[(size_t)row * HIDDEN + col]);
                float out = (1.f - zz) * nn + zz * h;
                if (F32OUT) outF[(size_t)row * HIDDEN + col] = out;
                else        outB[(size_t)row * HIDDEN + col] = f2bf(out);
            }
    }
}

extern "C" void kernel_launch(void* const* d_in, const int* in_sizes, int n_in,
                              void* d_out, int out_size, void* d_ws, size_t ws_size,
                              hipStream_t stream) {
    const int*   inputs = (const int*)d_in[0];
    const int*   A      = (const int*)d_in[1];
    const float* emb    = (const float*)d_in[2];
    const float* weight = (const float*)d_in[3];
    const float* w_ih   = (const float*)d_in[4];
    const float* w_hh   = (const float*)d_in[5];
    const float* b_ih   = (const float*)d_in[6];
    const float* b_hh   = (const float*)d_in[7];

    // ws: WihB 1.5 + WhhB 1.5 + Wb 1 + Wc 3 + bufA 51.2 + bufB 51.2 + sort 1.4 = ~111 MB
    // ax for layer 0 lives in d_out (51.2 of 102.4 MB); layer 1 ax reuses bufA.
    char* ws = (char*)d_ws;
    size_t off = 0;
    auto alloc = [&](size_t bytes) { void* p = ws + off; off += (bytes + 255) & ~255ull; return p; };
    ushort* WihB      = (ushort*)alloc((size_t)3 * HIDDEN * HIDDEN * sizeof(ushort));
    ushort* WhhB      = (ushort*)alloc((size_t)3 * HIDDEN * HIDDEN * sizeof(ushort));
    ushort* Wb        = (ushort*)alloc((size_t)2 * HIDDEN * HIDDEN * sizeof(ushort));
    ushort* Wc        = (ushort*)alloc((size_t)2 * 3 * HIDDEN * HIDDEN * sizeof(ushort));
    ushort* bufA      = (ushort*)alloc((size_t)N_NODES * HIDDEN * sizeof(ushort));
    ushort* bufB      = (ushort*)alloc((size_t)N_NODES * HIDDEN * sizeof(ushort));
    int*    count     = (int*)alloc((size_t)N_NODES * sizeof(int));
    int*    row_start = (int*)alloc((size_t)(N_NODES + 1) * sizeof(int));
    int*    cursor    = (int*)alloc((size_t)N_NODES * sizeof(int));
    int*    esrc      = (int*)alloc((size_t)N_EDGES * sizeof(int));
    ushort* ax0       = (ushort*)d_out;

    const int nW3 = 3 * HIDDEN * HIDDEN, nW2 = 2 * HIDDEN * HIDDEN;
    k_cvt8<<<(nW3 / 8 + 255) / 256, 256, 0, stream>>>(w_ih, WihB, nW3);
    k_cvt8<<<(nW3 / 8 + 255) / 256, 256, 0, stream>>>(w_hh, WhhB, nW3);
    k_cvt8<<<(nW2 / 8 + 255) / 256, 256, 0, stream>>>(weight, Wb, nW2);
    k_gemm_w<<<dim3(12, 4, 2), 256, 0, stream>>>(WihB, Wb, Wc);   // Wc_l = W_l @ w_ih^T

    k_gather<<<(N_NODES * 64 + 255) / 256, 256, 0, stream>>>(inputs, emb, bufA);

    hipMemsetAsync(count, 0, (size_t)N_NODES * sizeof(int), stream);
    k_hist<<<(N_EDGES + 255) / 256, 256, 0, stream>>>(inputs, A, count);
    k_scan<<<1, SCAN_T, 0, stream>>>(count, row_start, cursor);
    k_place<<<(N_EDGES + 255) / 256, 256, 0, stream>>>(inputs, A, cursor, esrc);

    dim3 gGru((N_NODES + 63) / 64, HIDDEN / 64);
    dim3 ga((N_NODES + 3) / 4);

    // Layer 0: ax0 = segsum(x0) -> d_out region; GRU(ax0, x0=bufA) -> bufB
    k_agg<<<ga, 256, 0, stream>>>(row_start, esrc, bufA, ax0);
    k_gru<false><<<gGru, 256, 0, stream>>>(ax0, bufA, Wc, WhhB, b_ih, b_hh, bufB, nullptr);

    // Layer 1: ax1 = segsum(x1) -> bufA (x0 dead); GRU(ax1, x1=bufB) -> f32 d_out
    k_agg<<<ga, 256, 0, stream>>>(row_start, esrc, bufB, bufA);
    k_gru<true><<<gGru, 256, 0, stream>>>(bufA, bufB, Wc + (size_t)3 * HIDDEN * HIDDEN,
                                          WhhB, b_ih, b_hh, nullptr, (float*)d_out);
}